// Round 13
// baseline (158.275 us; speedup 1.0000x reference)
//
#include <hip/hip_runtime.h>

#define NC 64      // channels / signal dim
#define NA 512     // dictionary atoms
#define KS 5       // sparsity

// ---- workspace layout in FLOATS (accum as double at 8B-aligned tail) ----
#define WS_DN   0        // Dn  [NC][NA]
#define WS_DNT  32768    // DnT [NA][NC]
#define WS_G    65536    // G   [NA][NA]
#define WS_ACCF 327680   // double accumulator lives here (byte off 1310720)

// out layout (FLOAT32): z_dl[2097152] | loss[1] | support[163840] | coeffs[163840]
#define OUT_LOSS 2097152
#define OUT_SUP  2097153
#define OUT_COF  2260993

__global__ void norm_kernel(const float* __restrict__ D, float* __restrict__ Dn,
                            float* __restrict__ DnT) {
  int n = blockIdx.x * 64 + threadIdx.x;
  float s = 0.f;
  for (int c = 0; c < NC; ++c) {
    float v = D[c * NA + n];
    s += v * v;
  }
  float den = fmaxf(sqrtf(s), 1e-10f);
  for (int c = 0; c < NC; c += 4) {
    float v0 = D[(c + 0) * NA + n] / den;
    float v1 = D[(c + 1) * NA + n] / den;
    float v2 = D[(c + 2) * NA + n] / den;
    float v3 = D[(c + 3) * NA + n] / den;
    Dn[(c + 0) * NA + n] = v0;
    Dn[(c + 1) * NA + n] = v1;
    Dn[(c + 2) * NA + n] = v2;
    Dn[(c + 3) * NA + n] = v3;
    *(float4*)&DnT[n * NC + c] = make_float4(v0, v1, v2, v3);
  }
}

// float4 gram: block i computes G row i; thread t owns atoms 4t..4t+3.
__global__ void gram_kernel(const float* __restrict__ Dn,
                            float* __restrict__ G, double* __restrict__ accum) {
  __shared__ float col[NC];
  int i = blockIdx.x, t = threadIdx.x;
  if (t < NC) col[t] = Dn[t * NA + i];
  if (i == 0 && t == 0) *accum = 0.0;
  __syncthreads();
  float4 s = make_float4(0.f, 0.f, 0.f, 0.f);
  const float4* Dn4 = (const float4*)Dn;
#pragma unroll
  for (int c = 0; c < NC; ++c) {
    float4 dv = Dn4[c * 128 + t];
    s.x += col[c] * dv.x; s.y += col[c] * dv.y;
    s.z += col[c] * dv.z; s.w += col[c] * dv.w;
  }
  ((float4*)(G + (size_t)i * NA))[t] = s;
}

// packed-friendly scalar-broadcast fma on a float2 (invites v_pk_fma_f32)
__device__ __forceinline__ float2 pkfma(float a, float2 b, float2 c) {
  float2 r;
  r.x = fmaf(a, b.x, c.x);
  r.y = fmaf(a, b.y, c.y);
  return r;
}

// One OMP iteration, QUARTER-WAVE parallel (R9/R10-proven).
// Lane ql (0..15) owns 32 atoms: slot s (0..31) <-> a = (s>>2)*64+4*ql+(s&3).
// R13 VGPR DIET: the 32-reg av[] is GONE -- masked |h| values are computed
// through the MVAL accessor in the max tree and RECOMPUTED at the equality
// rescan (bit-identical: same deterministic ops on unchanged inputs).
// -32 VGPR at the argmax peak (the kernel's high-water mark), +32 cheap
// VALU/step -- trades idle-issue slots for the registers that gate 3
// waves/SIMD occupancy.
// Delta refresh (R12-proven): h -= sum_j dg_j*G_j, no per-step park reload.
template<int KK>
__device__ __forceinline__ void omp_stepQ(
    const int ql, const float* __restrict__ G,
    const float* __restrict__ parkS,
    float (&h32)[32], unsigned &msk, int (&I)[KS],
    float (&Lo)[10], float (&rd)[KS], float (&y)[KS], float (&gam)[KS]) {
#define MVAL(s) (((msk >> (s)) & 1u) ? fabsf(h32[s]) : 0.f)
  // ---- value max: 8x4-ary leaves + 2-level root (folds to v_max3)
  float m8[8];
#pragma unroll
  for (int i = 0; i < 8; ++i)
    m8[i] = fmaxf(fmaxf(MVAL(4*i+0), MVAL(4*i+1)),
                  fmaxf(MVAL(4*i+2), MVAL(4*i+3)));
  float bv = fmaxf(fmaxf(fmaxf(m8[0], m8[1]), fmaxf(m8[2], m8[3])),
                   fmaxf(fmaxf(m8[4], m8[5]), fmaxf(m8[6], m8[7])));
#pragma unroll
  for (int off = 1; off < 16; off <<= 1)
    bv = fmaxf(bv, __shfl_xor(bv, off));
  // ---- lowest atom index achieving bv: min-tree of candidates (MVAL
  // recomputed; == comparison against the same deterministic values)
  int c8[8];
#pragma unroll
  for (int i = 0; i < 8; ++i) {
    const int base = (i << 6) + 4 * ql;          // (s>>2)*64 + 4*ql
    int c0 = (MVAL(4*i+0) == bv) ? (base + 0) : 0x7FFFFFFF;
    int c1 = (MVAL(4*i+1) == bv) ? (base + 1) : 0x7FFFFFFF;
    int c2 = (MVAL(4*i+2) == bv) ? (base + 2) : 0x7FFFFFFF;
    int c3 = (MVAL(4*i+3) == bv) ? (base + 3) : 0x7FFFFFFF;
    c8[i] = min(min(c0, c1), min(c2, c3));
  }
#undef MVAL
  int cand = min(min(min(c8[0], c8[1]), min(c8[2], c8[3])),
                 min(min(c8[4], c8[5]), min(c8[6], c8[7])));
#pragma unroll
  for (int off = 1; off < 16; off <<= 1)
    cand = min(cand, __shfl_xor(cand, off));
  const int idx = cand;                      // quarter-uniform
  if (((idx & 63) >> 2) == ql)
    msk &= ~(1u << (((idx >> 6) << 2) | (idx & 3)));
  I[KK] = idx;
  const float bk = parkS[idx];               // the step's only park read

  // ---- Cholesky rank-1 extension + incremental forward solve
  if constexpr (KK == 0) {
    rd[0] = 1.f;
    y[0] = bk * rd[0];
  } else {
    float Gc[KK], w_[KK];
#pragma unroll
    for (int j = 0; j < KK; ++j) Gc[j] = G[(size_t)I[j] * NA + idx];
#pragma unroll
    for (int i = 0; i < KK; ++i) {
      float ssum = Gc[i];
#pragma unroll
      for (int j = 0; j < i; ++j) ssum -= Lo[i*(i-1)/2 + j] * w_[j];
      w_[i] = ssum * rd[i];
    }
    float ww = 0.f;
#pragma unroll
    for (int i = 0; i < KK; ++i) ww += w_[i] * w_[i];
    float corner = sqrtf(fmaxf(1.f - ww, 1e-12f));
#pragma unroll
    for (int j = 0; j < KK; ++j) Lo[KK*(KK-1)/2 + j] = w_[j];
    rd[KK] = 1.f / corner;
    float fs = bk;                           // y_KK = (b_KK - w.y_prev)*rd_KK
#pragma unroll
    for (int j = 0; j < KK; ++j) fs -= w_[j] * y[j];
    y[KK] = fs * rd[KK];
  }

  // ---- backward solve from persistent y, capturing gamma deltas
  float dg[KK + 1];
#pragma unroll
  for (int i = KK; i >= 0; --i) {
    float g_ = y[i];
#pragma unroll
    for (int j = i + 1; j <= KK; ++j) g_ -= Lo[j*(j-1)/2 + i] * gam[j];
    g_ *= rd[i];
    dg[i] = (i == KK) ? g_ : (g_ - gam[i]);  // gam_KK^(KK-1) == 0
    gam[i] = g_;
  }

  // ---- delta h refresh: h32 -= sum_j dg_j * G[I_j]  (NO park reload)
  if constexpr (KK < 4) {
#pragma unroll
    for (int j = 0; j <= KK; ++j) {
      const float4* g4 = (const float4*)(G + (size_t)I[j] * NA);
      const float dj = dg[j];
#pragma unroll
      for (int i = 0; i < 8; ++i) {
        float4 g = g4[(i << 4) + ql];
        h32[i*4+0] -= dj * g.x; h32[i*4+1] -= dj * g.y;
        h32[i*4+2] -= dj * g.z; h32[i*4+3] -= dj * g.w;
      }
    }
  }
}

// 16 signals per block (phase 2: one per 16-lane QUARTER), grid 2048.
// __launch_bounds__(256, 3): 85-VGPR budget -> 3 waves/SIMD.  R12 arithmetic:
// phase 2 = ~1K-cycle serial chain per step, hidden by only 1.55 waves/SIMD
// (VGPR=124 capped 2/SIMD, 0.77x achieved); the chain pieces are proven
// irreducible (R10-R12 nulls), so deeper TLP is the remaining lever.  Live
// state after the av[] diet is ~82 regs -- fits the 85 budget (unlike R1's
// 110-vs-64).  WRITE_SIZE 9.664 MB is the no-spill tell.
// LDS: 32 KB park + 4 KB xsz + 128 B wsq = ~37 KB (4 blocks/CU -- not
// binding at 12 waves/CU target).
__global__ __launch_bounds__(256, 3) void omp_kernel(
    const float* __restrict__ z, const float* __restrict__ Dn,
    const float* __restrict__ DnT, const float* __restrict__ G,
    float* __restrict__ out, double* __restrict__ accum) {
  __shared__ __align__(16) float park[16 * NA];  // 32 KB h_bar park
  __shared__ __align__(16) float xsz[16 * NC];   // 4 KB: xs[s][c] then zout[c][s]
  __shared__ double wsq[16];
  const int t = threadIdx.x, lane = t & 63, wv = t >> 6;
  const int ql = lane & 15;
  const int m0 = blockIdx.x * 16;
  const int bh = m0 >> 6, b = bh >> 6, h = bh & 63, w0 = m0 & 63;
  const size_t zbase = (size_t)b * 262144 + (size_t)h * 64 + w0;

  // stage 16 signals coalesced: xsz[s*64+c]
  for (int j = t; j < 16 * NC; j += 256) {
    int c = j >> 4, s = j & 15;
    xsz[s * NC + c] = z[zbase + (size_t)c * 4096 + s];
  }
  __syncthreads();
  // this quarter's signal; epilogue channels 4*ql..4*ql+3 (float4-friendly)
  const int sig = (wv << 2) + (lane >> 4);
  const float4 xf4 = *(const float4*)&xsz[sig * NC + 4 * ql];
  // all xf4 reads complete before any phase-2 zout write (phase-1 barrier)

  // ---- phase 1: LDS-free h_bar GEMM (R5/R9-proven), float2-packed FMAs,
  // unroll 4 (R10 config -- best measured).
  {
    float2 acc2[16];
#pragma unroll
    for (int s = 0; s < 16; ++s) acc2[s] = make_float2(0.f, 0.f);

    const float2* Dn2 = (const float2*)Dn + (wv << 6) + lane;  // + c*256 per ch
    const float4* zp4 = (const float4*)(z + zbase);            // uniform base
#pragma unroll 4
    for (int c = 0; c < 64; ++c) {
      float2 dv = Dn2[c << 8];             // Dn[c][wv*128 + 2*lane + {0,1}]
      float4 xa = zp4[(c << 10) + 0];      // x[0..3][c]   (uniform -> s_load)
      float4 xb = zp4[(c << 10) + 1];      // x[4..7][c]
      float4 xc = zp4[(c << 10) + 2];      // x[8..11][c]
      float4 xd = zp4[(c << 10) + 3];      // x[12..15][c]
      acc2[ 0] = pkfma(xa.x, dv, acc2[ 0]);
      acc2[ 1] = pkfma(xa.y, dv, acc2[ 1]);
      acc2[ 2] = pkfma(xa.z, dv, acc2[ 2]);
      acc2[ 3] = pkfma(xa.w, dv, acc2[ 3]);
      acc2[ 4] = pkfma(xb.x, dv, acc2[ 4]);
      acc2[ 5] = pkfma(xb.y, dv, acc2[ 5]);
      acc2[ 6] = pkfma(xb.z, dv, acc2[ 6]);
      acc2[ 7] = pkfma(xb.w, dv, acc2[ 7]);
      acc2[ 8] = pkfma(xc.x, dv, acc2[ 8]);
      acc2[ 9] = pkfma(xc.y, dv, acc2[ 9]);
      acc2[10] = pkfma(xc.z, dv, acc2[10]);
      acc2[11] = pkfma(xc.w, dv, acc2[11]);
      acc2[12] = pkfma(xd.x, dv, acc2[12]);
      acc2[13] = pkfma(xd.y, dv, acc2[13]);
      acc2[14] = pkfma(xd.z, dv, acc2[14]);
      acc2[15] = pkfma(xd.w, dv, acc2[15]);
    }
    // park h_bar[sig][atom] (each wave writes its 128-atom slice of all 16)
    float2* park2 = (float2*)park;
#pragma unroll
    for (int s = 0; s < 16; ++s)
      park2[(s << 8) + (wv << 6) + lane] = acc2[s];
  }
  __syncthreads();                         // park complete (all waves)

  // ---- phase 2: OMP, one signal per 16-lane quarter
  const float* parkS = park + (size_t)sig * NA;
  float h32[32];
  {
    const float4* pk4 = (const float4*)parkS;
#pragma unroll
    for (int i = 0; i < 8; ++i) {          // h(0) = h_bar, read ONCE
      float4 hv = pk4[(i << 4) + ql];
      h32[i*4+0] = hv.x; h32[i*4+1] = hv.y; h32[i*4+2] = hv.z; h32[i*4+3] = hv.w;
    }
  }
  unsigned msk = 0xFFFFFFFFu;
  int I[KS];
  float Lo[10], rd[KS], y[KS], gam[KS];

  omp_stepQ<0>(ql, G, parkS, h32, msk, I, Lo, rd, y, gam);
  omp_stepQ<1>(ql, G, parkS, h32, msk, I, Lo, rd, y, gam);
  omp_stepQ<2>(ql, G, parkS, h32, msk, I, Lo, rd, y, gam);
  omp_stepQ<3>(ql, G, parkS, h32, msk, I, Lo, rd, y, gam);
  omp_stepQ<4>(ql, G, parkS, h32, msk, I, Lo, rd, y, gam);

  // ---- epilogue: this quarter's signal, channels 4*ql .. 4*ql+3
  float rr0 = 0.f, rr1 = 0.f, rr2 = 0.f, rr3 = 0.f;
#pragma unroll
  for (int j = 0; j < KS; ++j) {
    const float4 dvv = ((const float4*)(DnT + (size_t)I[j] * NC))[ql];
    rr0 += gam[j] * dvv.x; rr1 += gam[j] * dvv.y;
    rr2 += gam[j] * dvv.z; rr3 += gam[j] * dvv.w;
  }
  const float d0 = rr0 - xf4.x, d1 = rr1 - xf4.y;   // z_dl - z_e
  const float d2 = rr2 - xf4.z, d3 = rr3 - xf4.w;
  // zout[c][s] (xsz reuse; staging reads all finished before phase 1 barrier)
  xsz[(4 * ql + 0) * 16 + sig] = xf4.x + d0;
  xsz[(4 * ql + 1) * 16 + sig] = xf4.y + d1;
  xsz[(4 * ql + 2) * 16 + sig] = xf4.z + d2;
  xsz[(4 * ql + 3) * 16 + sig] = xf4.w + d3;
  double sq = (double)d0 * (double)d0 + (double)d1 * (double)d1
            + (double)d2 * (double)d2 + (double)d3 * (double)d3;
#pragma unroll
  for (int off = 1; off < 16; off <<= 1) sq += __shfl_xor(sq, off);
  if (ql == 0) wsq[sig] = sq;

  // support / coeffs: constant-index selection chains only
  if (ql < KS) {
    int   iv = I[0];
    float gv = gam[0];
    if (ql == 1) { iv = I[1]; gv = gam[1]; }
    if (ql == 2) { iv = I[2]; gv = gam[2]; }
    if (ql == 3) { iv = I[3]; gv = gam[3]; }
    if (ql == 4) { iv = I[4]; gv = gam[4]; }
    const int m = m0 + sig;
    out[OUT_SUP + (size_t)m * KS + ql] = (float)iv;
    out[OUT_COF + (size_t)m * KS + ql] = gv;
  }

  __syncthreads();
  // coalesced z_dl store from zout (xsz[c*16+s])
  for (int j = t; j < 16 * NC; j += 256) {
    int c = j >> 4, s = j & 15;
    out[zbase + (size_t)c * 4096 + s] = xsz[j];
  }
  if (t == 0) {
    double ssum = 0.0;
#pragma unroll
    for (int i = 0; i < 16; ++i) ssum += wsq[i];
    atomicAdd(accum, ssum);
  }
}

__global__ void final_kernel(const double* __restrict__ accum, float* __restrict__ out) {
  double mse = *accum / 2097152.0;
  out[OUT_LOSS] = (float)(mse + 0.25 * mse);
}

extern "C" void kernel_launch(void* const* d_in, const int* in_sizes, int n_in,
                              void* d_out, int out_size, void* d_ws, size_t ws_size,
                              hipStream_t stream) {
  const float* z_e = (const float*)d_in[0];
  const float* dic = (const float*)d_in[1];
  float* out = (float*)d_out;
  float* ws = (float*)d_ws;
  float* Dn   = ws + WS_DN;
  float* DnT  = ws + WS_DNT;
  float* G    = ws + WS_G;
  double* accu = (double*)(ws + WS_ACCF);

  hipLaunchKernelGGL(norm_kernel,  dim3(8),    dim3(64),  0, stream, dic, Dn, DnT);
  hipLaunchKernelGGL(gram_kernel,  dim3(NA),   dim3(128), 0, stream, Dn, G, accu);
  hipLaunchKernelGGL(omp_kernel,   dim3(2048), dim3(256), 0, stream,
                     z_e, Dn, DnT, G, out, accu);
  hipLaunchKernelGGL(final_kernel, dim3(1),    dim3(1),   0, stream, accu, out);
}

// Round 14
// 141.243 us; speedup vs baseline: 1.1206x; 1.1206x over previous
//
#include <hip/hip_runtime.h>

#define NC 64      // channels / signal dim
#define NA 512     // dictionary atoms
#define KS 5       // sparsity

// ---- workspace layout in FLOATS (accum as double at 8B-aligned tail) ----
#define WS_DN   0        // Dn  [NC][NA]
#define WS_DNT  32768    // DnT [NA][NC]
#define WS_G    65536    // G   [NA][NA]
#define WS_ACCF 327680   // double accumulator lives here (byte off 1310720)

// out layout (FLOAT32): z_dl[2097152] | loss[1] | support[163840] | coeffs[163840]
#define OUT_LOSS 2097152
#define OUT_SUP  2097153
#define OUT_COF  2260993

__global__ void norm_kernel(const float* __restrict__ D, float* __restrict__ Dn,
                            float* __restrict__ DnT) {
  int n = blockIdx.x * 64 + threadIdx.x;
  float s = 0.f;
  for (int c = 0; c < NC; ++c) {
    float v = D[c * NA + n];
    s += v * v;
  }
  float den = fmaxf(sqrtf(s), 1e-10f);
  for (int c = 0; c < NC; c += 4) {
    float v0 = D[(c + 0) * NA + n] / den;
    float v1 = D[(c + 1) * NA + n] / den;
    float v2 = D[(c + 2) * NA + n] / den;
    float v3 = D[(c + 3) * NA + n] / den;
    Dn[(c + 0) * NA + n] = v0;
    Dn[(c + 1) * NA + n] = v1;
    Dn[(c + 2) * NA + n] = v2;
    Dn[(c + 3) * NA + n] = v3;
    *(float4*)&DnT[n * NC + c] = make_float4(v0, v1, v2, v3);
  }
}

// float4 gram: block i computes G row i; thread t owns atoms 4t..4t+3.
__global__ void gram_kernel(const float* __restrict__ Dn,
                            float* __restrict__ G, double* __restrict__ accum) {
  __shared__ float col[NC];
  int i = blockIdx.x, t = threadIdx.x;
  if (t < NC) col[t] = Dn[t * NA + i];
  if (i == 0 && t == 0) *accum = 0.0;
  __syncthreads();
  float4 s = make_float4(0.f, 0.f, 0.f, 0.f);
  const float4* Dn4 = (const float4*)Dn;
#pragma unroll
  for (int c = 0; c < NC; ++c) {
    float4 dv = Dn4[c * 128 + t];
    s.x += col[c] * dv.x; s.y += col[c] * dv.y;
    s.z += col[c] * dv.z; s.w += col[c] * dv.w;
  }
  ((float4*)(G + (size_t)i * NA))[t] = s;
}

// packed-friendly scalar-broadcast fma on a float2 (invites v_pk_fma_f32)
__device__ __forceinline__ float2 pkfma(float a, float2 b, float2 c) {
  float2 r;
  r.x = fmaf(a, b.x, c.x);
  r.y = fmaf(a, b.y, c.y);
  return r;
}

// One OMP iteration, QUARTER-WAVE parallel (R9/R10-proven).
// Lane ql (0..15) owns 32 atoms: slot s (0..31) <-> a = (s>>2)*64+4*ql+(s&3).
// Argmax: R10's split tree form (best measured across R10-R13 variants).
// Delta refresh (R12): h^(k) = h^(k-1) - sum_j (gam_j^(k)-gam_j^(k-1))*G_j;
// no per-step park reload, h32 lives in registers across all 5 steps.
// R13 post-mortem: true peak live state ~95-100 regs -- any budget below
// that (R13's 85) spills ~100 MB scratch; (256,2) is the correct pin.
template<int KK>
__device__ __forceinline__ void omp_stepQ(
    const int ql, const float* __restrict__ G,
    const float* __restrict__ parkS,
    float (&h32)[32], unsigned &msk, int (&I)[KS],
    float (&Lo)[10], float (&rd)[KS], float (&y)[KS], float (&gam)[KS]) {
  // ---- masked |h|
  float av[32];
#pragma unroll
  for (int s = 0; s < 32; ++s)
    av[s] = ((msk >> s) & 1u) ? fabsf(h32[s]) : 0.f;
  // ---- value max: 8x4-ary leaves + 2-level root (folds to v_max3)
  float m8[8];
#pragma unroll
  for (int i = 0; i < 8; ++i)
    m8[i] = fmaxf(fmaxf(av[4*i], av[4*i+1]), fmaxf(av[4*i+2], av[4*i+3]));
  float bv = fmaxf(fmaxf(fmaxf(m8[0], m8[1]), fmaxf(m8[2], m8[3])),
                   fmaxf(fmaxf(m8[4], m8[5]), fmaxf(m8[6], m8[7])));
#pragma unroll
  for (int off = 1; off < 16; off <<= 1)
    bv = fmaxf(bv, __shfl_xor(bv, off));
  // ---- lowest atom index achieving bv: min-tree of candidates
  int c8[8];
#pragma unroll
  for (int i = 0; i < 8; ++i) {
    const int base = (i << 6) + 4 * ql;          // (s>>2)*64 + 4*ql
    int c0 = (av[4*i+0] == bv) ? (base + 0) : 0x7FFFFFFF;
    int c1 = (av[4*i+1] == bv) ? (base + 1) : 0x7FFFFFFF;
    int c2 = (av[4*i+2] == bv) ? (base + 2) : 0x7FFFFFFF;
    int c3 = (av[4*i+3] == bv) ? (base + 3) : 0x7FFFFFFF;
    c8[i] = min(min(c0, c1), min(c2, c3));
  }
  int cand = min(min(min(c8[0], c8[1]), min(c8[2], c8[3])),
                 min(min(c8[4], c8[5]), min(c8[6], c8[7])));
#pragma unroll
  for (int off = 1; off < 16; off <<= 1)
    cand = min(cand, __shfl_xor(cand, off));
  const int idx = cand;                      // quarter-uniform
  if (((idx & 63) >> 2) == ql)
    msk &= ~(1u << (((idx >> 6) << 2) | (idx & 3)));
  I[KK] = idx;
  const float bk = parkS[idx];               // the step's only park read

  // ---- Cholesky rank-1 extension + incremental forward solve
  if constexpr (KK == 0) {
    rd[0] = 1.f;
    y[0] = bk * rd[0];
  } else {
    float Gc[KK], w_[KK];
#pragma unroll
    for (int j = 0; j < KK; ++j) Gc[j] = G[(size_t)I[j] * NA + idx];
#pragma unroll
    for (int i = 0; i < KK; ++i) {
      float ssum = Gc[i];
#pragma unroll
      for (int j = 0; j < i; ++j) ssum -= Lo[i*(i-1)/2 + j] * w_[j];
      w_[i] = ssum * rd[i];
    }
    float ww = 0.f;
#pragma unroll
    for (int i = 0; i < KK; ++i) ww += w_[i] * w_[i];
    float corner = sqrtf(fmaxf(1.f - ww, 1e-12f));
#pragma unroll
    for (int j = 0; j < KK; ++j) Lo[KK*(KK-1)/2 + j] = w_[j];
    rd[KK] = 1.f / corner;
    float fs = bk;                           // y_KK = (b_KK - w.y_prev)*rd_KK
#pragma unroll
    for (int j = 0; j < KK; ++j) fs -= w_[j] * y[j];
    y[KK] = fs * rd[KK];
  }

  // ---- backward solve from persistent y, capturing gamma deltas
  float dg[KK + 1];
#pragma unroll
  for (int i = KK; i >= 0; --i) {
    float g_ = y[i];
#pragma unroll
    for (int j = i + 1; j <= KK; ++j) g_ -= Lo[j*(j-1)/2 + i] * gam[j];
    g_ *= rd[i];
    dg[i] = (i == KK) ? g_ : (g_ - gam[i]);  // gam_KK^(KK-1) == 0
    gam[i] = g_;
  }

  // ---- delta h refresh: h32 -= sum_j dg_j * G[I_j]  (NO park reload)
  if constexpr (KK < 4) {
#pragma unroll
    for (int j = 0; j <= KK; ++j) {
      const float4* g4 = (const float4*)(G + (size_t)I[j] * NA);
      const float dj = dg[j];
#pragma unroll
      for (int i = 0; i < 8; ++i) {
        float4 g = g4[(i << 4) + ql];
        h32[i*4+0] -= dj * g.x; h32[i*4+1] -= dj * g.y;
        h32[i*4+2] -= dj * g.z; h32[i*4+3] -= dj * g.w;
      }
    }
  }
}

// 16 signals per block (phase 2: one per 16-lane QUARTER), grid 2048.
// LDS: 32 KB park + 4 KB xsz + 128 B wsq = ~37 KB.  Fat-wave ILP is the
// proven lever (R8-R13); (256,2) keeps the 128-VGPR cap -- the ONLY
// non-spilling budget for this structure's ~95-100 live regs (R13 evidence).
// WRITE_SIZE 9.664 MB is the no-spill tell.
__global__ __launch_bounds__(256, 2) void omp_kernel(
    const float* __restrict__ z, const float* __restrict__ Dn,
    const float* __restrict__ DnT, const float* __restrict__ G,
    float* __restrict__ out, double* __restrict__ accum) {
  __shared__ __align__(16) float park[16 * NA];  // 32 KB h_bar park
  __shared__ __align__(16) float xsz[16 * NC];   // 4 KB: xs[s][c] then zout[c][s]
  __shared__ double wsq[16];
  const int t = threadIdx.x, lane = t & 63, wv = t >> 6;
  const int ql = lane & 15;
  const int m0 = blockIdx.x * 16;
  const int bh = m0 >> 6, b = bh >> 6, h = bh & 63, w0 = m0 & 63;
  const size_t zbase = (size_t)b * 262144 + (size_t)h * 64 + w0;

  // stage 16 signals coalesced: xsz[s*64+c]
  for (int j = t; j < 16 * NC; j += 256) {
    int c = j >> 4, s = j & 15;
    xsz[s * NC + c] = z[zbase + (size_t)c * 4096 + s];
  }
  __syncthreads();
  // this quarter's signal; epilogue channels 4*ql..4*ql+3 (float4-friendly)
  const int sig = (wv << 2) + (lane >> 4);
  const float4 xf4 = *(const float4*)&xsz[sig * NC + 4 * ql];
  // all xf4 reads complete before any phase-2 zout write (phase-1 barrier)

  // ---- phase 1: LDS-free h_bar GEMM (R5/R9-proven), float2-packed FMAs,
  // unroll 4 (R10 config -- best measured; unroll 8 regressed in R11).
  {
    float2 acc2[16];
#pragma unroll
    for (int s = 0; s < 16; ++s) acc2[s] = make_float2(0.f, 0.f);

    const float2* Dn2 = (const float2*)Dn + (wv << 6) + lane;  // + c*256 per ch
    const float4* zp4 = (const float4*)(z + zbase);            // uniform base
#pragma unroll 4
    for (int c = 0; c < 64; ++c) {
      float2 dv = Dn2[c << 8];             // Dn[c][wv*128 + 2*lane + {0,1}]
      float4 xa = zp4[(c << 10) + 0];      // x[0..3][c]   (uniform -> s_load)
      float4 xb = zp4[(c << 10) + 1];      // x[4..7][c]
      float4 xc = zp4[(c << 10) + 2];      // x[8..11][c]
      float4 xd = zp4[(c << 10) + 3];      // x[12..15][c]
      acc2[ 0] = pkfma(xa.x, dv, acc2[ 0]);
      acc2[ 1] = pkfma(xa.y, dv, acc2[ 1]);
      acc2[ 2] = pkfma(xa.z, dv, acc2[ 2]);
      acc2[ 3] = pkfma(xa.w, dv, acc2[ 3]);
      acc2[ 4] = pkfma(xb.x, dv, acc2[ 4]);
      acc2[ 5] = pkfma(xb.y, dv, acc2[ 5]);
      acc2[ 6] = pkfma(xb.z, dv, acc2[ 6]);
      acc2[ 7] = pkfma(xb.w, dv, acc2[ 7]);
      acc2[ 8] = pkfma(xc.x, dv, acc2[ 8]);
      acc2[ 9] = pkfma(xc.y, dv, acc2[ 9]);
      acc2[10] = pkfma(xc.z, dv, acc2[10]);
      acc2[11] = pkfma(xc.w, dv, acc2[11]);
      acc2[12] = pkfma(xd.x, dv, acc2[12]);
      acc2[13] = pkfma(xd.y, dv, acc2[13]);
      acc2[14] = pkfma(xd.z, dv, acc2[14]);
      acc2[15] = pkfma(xd.w, dv, acc2[15]);
    }
    // park h_bar[sig][atom] (each wave writes its 128-atom slice of all 16)
    float2* park2 = (float2*)park;
#pragma unroll
    for (int s = 0; s < 16; ++s)
      park2[(s << 8) + (wv << 6) + lane] = acc2[s];
  }
  __syncthreads();                         // park complete (all waves)

  // ---- phase 2: OMP, one signal per 16-lane quarter
  const float* parkS = park + (size_t)sig * NA;
  float h32[32];
  {
    const float4* pk4 = (const float4*)parkS;
#pragma unroll
    for (int i = 0; i < 8; ++i) {          // h(0) = h_bar, read ONCE
      float4 hv = pk4[(i << 4) + ql];
      h32[i*4+0] = hv.x; h32[i*4+1] = hv.y; h32[i*4+2] = hv.z; h32[i*4+3] = hv.w;
    }
  }
  unsigned msk = 0xFFFFFFFFu;
  int I[KS];
  float Lo[10], rd[KS], y[KS], gam[KS];

  omp_stepQ<0>(ql, G, parkS, h32, msk, I, Lo, rd, y, gam);
  omp_stepQ<1>(ql, G, parkS, h32, msk, I, Lo, rd, y, gam);
  omp_stepQ<2>(ql, G, parkS, h32, msk, I, Lo, rd, y, gam);
  omp_stepQ<3>(ql, G, parkS, h32, msk, I, Lo, rd, y, gam);
  omp_stepQ<4>(ql, G, parkS, h32, msk, I, Lo, rd, y, gam);

  // ---- epilogue: this quarter's signal, channels 4*ql .. 4*ql+3
  float rr0 = 0.f, rr1 = 0.f, rr2 = 0.f, rr3 = 0.f;
#pragma unroll
  for (int j = 0; j < KS; ++j) {
    const float4 dvv = ((const float4*)(DnT + (size_t)I[j] * NC))[ql];
    rr0 += gam[j] * dvv.x; rr1 += gam[j] * dvv.y;
    rr2 += gam[j] * dvv.z; rr3 += gam[j] * dvv.w;
  }
  const float d0 = rr0 - xf4.x, d1 = rr1 - xf4.y;   // z_dl - z_e
  const float d2 = rr2 - xf4.z, d3 = rr3 - xf4.w;
  // zout[c][s] (xsz reuse; staging reads all finished before phase 1 barrier)
  xsz[(4 * ql + 0) * 16 + sig] = xf4.x + d0;
  xsz[(4 * ql + 1) * 16 + sig] = xf4.y + d1;
  xsz[(4 * ql + 2) * 16 + sig] = xf4.z + d2;
  xsz[(4 * ql + 3) * 16 + sig] = xf4.w + d3;
  double sq = (double)d0 * (double)d0 + (double)d1 * (double)d1
            + (double)d2 * (double)d2 + (double)d3 * (double)d3;
#pragma unroll
  for (int off = 1; off < 16; off <<= 1) sq += __shfl_xor(sq, off);
  if (ql == 0) wsq[sig] = sq;

  // support / coeffs: constant-index selection chains only
  if (ql < KS) {
    int   iv = I[0];
    float gv = gam[0];
    if (ql == 1) { iv = I[1]; gv = gam[1]; }
    if (ql == 2) { iv = I[2]; gv = gam[2]; }
    if (ql == 3) { iv = I[3]; gv = gam[3]; }
    if (ql == 4) { iv = I[4]; gv = gam[4]; }
    const int m = m0 + sig;
    out[OUT_SUP + (size_t)m * KS + ql] = (float)iv;
    out[OUT_COF + (size_t)m * KS + ql] = gv;
  }

  __syncthreads();
  // coalesced z_dl store from zout (xsz[c*16+s])
  for (int j = t; j < 16 * NC; j += 256) {
    int c = j >> 4, s = j & 15;
    out[zbase + (size_t)c * 4096 + s] = xsz[j];
  }
  if (t == 0) {
    double ssum = 0.0;
#pragma unroll
    for (int i = 0; i < 16; ++i) ssum += wsq[i];
    atomicAdd(accum, ssum);
  }
}

__global__ void final_kernel(const double* __restrict__ accum, float* __restrict__ out) {
  double mse = *accum / 2097152.0;
  out[OUT_LOSS] = (float)(mse + 0.25 * mse);
}

extern "C" void kernel_launch(void* const* d_in, const int* in_sizes, int n_in,
                              void* d_out, int out_size, void* d_ws, size_t ws_size,
                              hipStream_t stream) {
  const float* z_e = (const float*)d_in[0];
  const float* dic = (const float*)d_in[1];
  float* out = (float*)d_out;
  float* ws = (float*)d_ws;
  float* Dn   = ws + WS_DN;
  float* DnT  = ws + WS_DNT;
  float* G    = ws + WS_G;
  double* accu = (double*)(ws + WS_ACCF);

  hipLaunchKernelGGL(norm_kernel,  dim3(8),    dim3(64),  0, stream, dic, Dn, DnT);
  hipLaunchKernelGGL(gram_kernel,  dim3(NA),   dim3(128), 0, stream, Dn, G, accu);
  hipLaunchKernelGGL(omp_kernel,   dim3(2048), dim3(256), 0, stream,
                     z_e, Dn, DnT, G, out, accu);
  hipLaunchKernelGGL(final_kernel, dim3(1),    dim3(1),   0, stream, accu, out);
}